// Round 6
// baseline (237.303 us; speedup 1.0000x reference)
//
#include <hip/hip_runtime.h>

// NMS 2D, 3x3 window, replicate padding, center excluded, max seeded with 0.
// x: (8, 64, 256, 256) fp32.  out[p] = x[p] if x[p] > max(0, 8 neighbors) else 0.
//
// R6: wave-private software pipeline, NO barriers, NO vmcnt(0) drains.
// R1-R4 (register kernels) and R5 (block-LDS + __syncthreads convoy) all hit
// ~79-85 us. R5's barrier forces a full vmcnt drain each strip (the m97
// problem). Here each wave owns 2 private 10-row LDS buffers and pipelines:
//   DMA strip s+1 -> buf B | s_waitcnt vmcnt(10) (strip s ready, s+1 still
//   in flight) | compute strip s from buf A | 8 nontemporal stores | swap.
// No cross-wave LDS sharing => no __syncthreads needed => steady-state mixed
// read/write stream like the 6.7 TB/s fill / 6.3 TB/s copy kernels.

#define NMS_H 256
#define NMS_W 256
#define PLANE (NMS_H * NMS_W)
#define SROWS 8                      // output rows per strip
#define LROWS 10                     // staged rows (SROWS + 2 vertical halo)
#define NSTRIPS 8                    // strips per wave (64 rows per wave)
#define BUF_WORDS (LROWS * NMS_W)    // 2560 floats = 10 KB per buffer

typedef float f4_t __attribute__((ext_vector_type(4)));
typedef __attribute__((address_space(3))) float lds_f;
typedef const __attribute__((address_space(1))) float glob_f;

struct HV {
    float4 h;   // horizontal max-of-3 per pixel (includes center)
    float4 lr;  // horizontal max of left+right only (center excluded)
};

__device__ __forceinline__ HV rowmax(const float4 v, const int tx) {
    float l = __shfl_up(v.w, 1, 64);    // last elem of lane tx-1
    float r = __shfl_down(v.x, 1, 64);  // first elem of lane tx+1
    if (tx == 0)  l = v.x;              // replicate pad left edge
    if (tx == 63) r = v.w;              // replicate pad right edge
    HV o;
    o.h.x = fmaxf(l,   fmaxf(v.x, v.y));
    o.h.y = fmaxf(v.x, fmaxf(v.y, v.z));
    o.h.z = fmaxf(v.y, fmaxf(v.z, v.w));
    o.h.w = fmaxf(v.z, fmaxf(v.w, r));
    o.lr.x = fmaxf(l,   v.y);
    o.lr.y = fmaxf(v.x, v.z);
    o.lr.z = fmaxf(v.y, v.w);
    o.lr.w = fmaxf(v.z, r);
    return o;
}

// DMA one strip (rows r0-1 .. r0+SROWS, clamped) into a wave-private buffer.
// Fire-and-forget: 10 global_load_lds_dwordx4, tracked only by vmcnt.
__device__ __forceinline__ void dma_strip(const float* pl, int r0,
                                          lds_f* buf, int col4) {
    #pragma unroll
    for (int j = 0; j < LROWS; ++j) {
        const int r = min(max(r0 + j - 1, 0), NMS_H - 1);
        glob_f* g = (glob_f*)(pl + r * NMS_W + col4);
        __builtin_amdgcn_global_load_lds(g, buf + j * NMS_W, 16, 0, 0);
    }
}

__global__ __launch_bounds__(128) void nms2d_kernel(const float* __restrict__ x,
                                                    float* __restrict__ out) {
    // 2 waves/block, each wave fully independent. 40 KB LDS -> 4 blocks/CU.
    __shared__ float lds[2][2][BUF_WORDS];

    const int tx   = threadIdx.x;        // 0..63
    const int ty   = threadIdx.y;        // 0..1 (wave id in block)
    const int col4 = tx * 4;
    const int w    = blockIdx.x * 2 + ty;   // 0..2047
    const int plane_idx = w >> 2;           // 512 planes
    const int row_base  = (w & 3) * (NSTRIPS * SROWS);  // quarter: 64 rows

    const float* pl = x   + (size_t)plane_idx * PLANE;
    float*       op = out + (size_t)plane_idx * PLANE;

    lds_f* buf0 = (lds_f*)&lds[ty][0][0];
    lds_f* buf1 = (lds_f*)&lds[ty][1][0];

    // Prologue: stage strip 0.
    dma_strip(pl, row_base, buf0, col4);

    #pragma unroll
    for (int s = 0; s < NSTRIPS; ++s) {
        lds_f* cur = (s & 1) ? buf1 : buf0;
        lds_f* nxt = (s & 1) ? buf0 : buf1;

        if (s + 1 < NSTRIPS) {
            // Prefetch next strip, then wait only for the CURRENT strip's
            // 10 DMAs (leave the 10 just-issued in flight).
            dma_strip(pl, row_base + (s + 1) * SROWS, nxt, col4);
            asm volatile("s_waitcnt vmcnt(10)" ::: "memory");
        } else {
            asm volatile("s_waitcnt vmcnt(0)" ::: "memory");
        }

        // Read the 10 staged rows (wave-private, no bank conflicts: lane i
        // reads bytes 16i..16i+15 of each 1 KB row).
        float4 v[LROWS];
        #pragma unroll
        for (int j = 0; j < LROWS; ++j)
            v[j] = *reinterpret_cast<const float4*>((const float*)(cur + j * NMS_W + col4));

        // Rolling separable max over the 10 rows -> 8 output rows.
        HV a = rowmax(v[0], tx);
        HV b = rowmax(v[1], tx);
        #pragma unroll
        for (int i = 0; i < SROWS; ++i) {
            HV c = rowmax(v[i + 2], tx);
            const float4 ctr = v[i + 1];
            f4_t o;
            float m;
            m = fmaxf(0.0f, fmaxf(fmaxf(a.h.x, c.h.x), b.lr.x)); o.x = (ctr.x > m) ? ctr.x : 0.0f;
            m = fmaxf(0.0f, fmaxf(fmaxf(a.h.y, c.h.y), b.lr.y)); o.y = (ctr.y > m) ? ctr.y : 0.0f;
            m = fmaxf(0.0f, fmaxf(fmaxf(a.h.z, c.h.z), b.lr.z)); o.z = (ctr.z > m) ? ctr.z : 0.0f;
            m = fmaxf(0.0f, fmaxf(fmaxf(a.h.w, c.h.w), b.lr.w)); o.w = (ctr.w > m) ? ctr.w : 0.0f;
            __builtin_nontemporal_store(o,
                reinterpret_cast<f4_t*>(op + (row_base + s * SROWS + i) * NMS_W + col4));
            a = b; b = c;
        }
    }
}

extern "C" void kernel_launch(void* const* d_in, const int* in_sizes, int n_in,
                              void* d_out, int out_size, void* d_ws, size_t ws_size,
                              hipStream_t stream) {
    const float* x = (const float*)d_in[0];
    float* out = (float*)d_out;

    // 1024 blocks x 2 waves = 2048 waves; each owns a 64-row plane-quarter.
    // 40 KB LDS/block -> 4 blocks/CU resident, steady-state pipeline.
    dim3 block(64, 2);
    dim3 grid(1024);
    nms2d_kernel<<<grid, block, 0, stream>>>(x, out);
}

// Round 7
// 226.044 us; speedup vs baseline: 1.0498x; 1.0498x over previous
//
#include <hip/hip_runtime.h>

// NMS 2D, 3x3 window, replicate padding, center excluded, max seeded with 0.
// x: (8, 64, 256, 256) fp32.  out[p] = x[p] if x[p] > max(0, 8 neighbors) else 0.
//
// R7: loop-free copy-shaped kernel. R1-R4 (register, looped) all hit 80-85 us
// / 2.5 TB/s; R5/R6 (LDS staging) were worse. Remaining suspect: per-wave
// loop serialization (in-order vmcnt queue shared by loads+stores => each
// iteration costs ~ a memory round-trip). Here a thread does exactly:
//   3 independent row loads -> 6 shuffles + ~20 fmax -> 1 store -> exit.
// No loop, no carried state. 32768 blocks stream through the CUs like the
// 6.7 TB/s fill kernel. XCD swizzle keeps each plane's blocks (and its 3x
// vertical re-reads) on one XCD's L2.

#define NMS_H 256
#define NMS_W 256
#define PLANE (NMS_H * NMS_W)

typedef float f4_t __attribute__((ext_vector_type(4)));

struct HV {
    float4 h;   // horizontal max-of-3 per pixel (includes center)
    float4 lr;  // horizontal max of left+right only (center excluded)
};

__device__ __forceinline__ HV rowmax(const float4 v, const int tx) {
    float l = __shfl_up(v.w, 1, 64);    // last elem of lane tx-1
    float r = __shfl_down(v.x, 1, 64);  // first elem of lane tx+1
    if (tx == 0)  l = v.x;              // replicate pad left edge
    if (tx == 63) r = v.w;              // replicate pad right edge
    HV o;
    o.h.x = fmaxf(l,   fmaxf(v.x, v.y));
    o.h.y = fmaxf(v.x, fmaxf(v.y, v.z));
    o.h.z = fmaxf(v.y, fmaxf(v.z, v.w));
    o.h.w = fmaxf(v.z, fmaxf(v.w, r));
    o.lr.x = fmaxf(l,   v.y);
    o.lr.y = fmaxf(v.x, v.z);
    o.lr.z = fmaxf(v.y, v.w);
    o.lr.w = fmaxf(v.z, r);
    return o;
}

__global__ __launch_bounds__(256) void nms2d_kernel(const float* __restrict__ x,
                                                    float* __restrict__ out) {
    // XCD swizzle: blocks dispatch round-robin across 8 XCDs (blk % 8).
    // Remap so XCD k owns planes [k*64, (k+1)*64) -> vertical halo re-reads
    // stay in that XCD's L2 (one plane = 256 KB << 4 MB).
    const int blk     = blockIdx.x;
    const int logical = (blk >> 3) + (blk & 7) * (32768 / 8);

    const int plane_idx = logical >> 6;        // 512 planes
    const int rg        = logical & 63;        // 64 row-groups of 4 rows
    const int tx        = threadIdx.x & 63;    // float4 column-group
    const int r         = rg * 4 + (threadIdx.x >> 6);  // this wave's row
    const int col4      = tx * 4;

    const float* pl = x + (size_t)plane_idx * PLANE;

    // 3 independent clamped row loads — the thread's entire read set.
    const int rm = max(r - 1, 0);
    const int rp = min(r + 1, NMS_H - 1);
    const float4 va = *reinterpret_cast<const float4*>(pl + rm * NMS_W + col4);
    const float4 vc = *reinterpret_cast<const float4*>(pl + r  * NMS_W + col4);
    const float4 vb = *reinterpret_cast<const float4*>(pl + rp * NMS_W + col4);

    const HV ma = rowmax(va, tx);
    const HV mc = rowmax(vc, tx);
    const HV mb = rowmax(vb, tx);

    f4_t o;
    float m;
    m = fmaxf(0.0f, fmaxf(fmaxf(ma.h.x, mb.h.x), mc.lr.x)); o.x = (vc.x > m) ? vc.x : 0.0f;
    m = fmaxf(0.0f, fmaxf(fmaxf(ma.h.y, mb.h.y), mc.lr.y)); o.y = (vc.y > m) ? vc.y : 0.0f;
    m = fmaxf(0.0f, fmaxf(fmaxf(ma.h.z, mb.h.z), mc.lr.z)); o.z = (vc.z > m) ? vc.z : 0.0f;
    m = fmaxf(0.0f, fmaxf(fmaxf(ma.h.w, mb.h.w), mc.lr.w)); o.w = (vc.w > m) ? vc.w : 0.0f;

    *reinterpret_cast<f4_t*>(out + (size_t)plane_idx * PLANE + r * NMS_W + col4) = o;
}

extern "C" void kernel_launch(void* const* d_in, const int* in_sizes, int n_in,
                              void* d_out, int out_size, void* d_ws, size_t ws_size,
                              hipStream_t stream) {
    const float* x = (const float*)d_in[0];
    float* out = (float*)d_out;

    // One thread per output float4: 512 planes x 64 row-groups = 32768 blocks.
    dim3 block(256);
    dim3 grid(32768);
    nms2d_kernel<<<grid, block, 0, stream>>>(x, out);
}